// Round 7
// baseline (319.914 us; speedup 1.0000x reference)
//
#include <hip/hip_runtime.h>
#include <hip/hip_fp16.h>

#define N_NODES 50000
#define N_EDGES 800000
#define F_IN 128
#define HID 64
#define N_GRAPHS 64

#define SCAN_B ((N_NODES + 255) / 256)     // 196 blocks
#define FUSE_B ((N_EDGES + 255) / 256)     // 3125 blocks; == N_NODES/16 exactly

typedef _Float16 half8 __attribute__((ext_vector_type(8)));
typedef float f32x4 __attribute__((ext_vector_type(4)));

// ---------------- degree (int4 over contiguous dst) + one-time weight pack ----------------
__global__ void deg_pack(const int* __restrict__ ei, int* __restrict__ ideg, int E,
                         const float* __restrict__ W1, const float* __restrict__ W2,
                         const float* __restrict__ W3,
                         __half* __restrict__ W1t, __half* __restrict__ W2t,
                         __half* __restrict__ W3t) {
    int i = blockIdx.x * blockDim.x + threadIdx.x;
    if (i * 4 < E) {
        int4 d = ((const int4*)(ei + E))[i];   // dst row contiguous
        atomicAdd(&ideg[d.x], 1);
        atomicAdd(&ideg[d.y], 1);
        atomicAdd(&ideg[d.z], 1);
        atomicAdd(&ideg[d.w], 1);
    }
    // fold: transpose+cast weights (16384 lanes; first 64 blocks)
    if (i < 8192) {                                   // W1t: [64 f][128 k]
        int f = i >> 7, k = i & 127;
        W1t[i] = __float2half(W1[k * 64 + f]);
    } else if (i < 12288) {                           // W2t: [64 f][64 k]
        int j = i - 8192;
        int f = j >> 6, k = j & 63;
        W2t[j] = __float2half(W2[k * 64 + f]);
    } else if (i < 16384) {                           // W3t: [64 f][64 k]
        int l = i - 12288;
        int f = l >> 6, k = l & 63;
        W3t[l] = __float2half(W3[k * 64 + f]);
    }
}

// ---------------- scan phase 1: per-block sums (+ fold: zero pooling buffers) ----------------
__global__ void scan_part(const int* __restrict__ ideg, int* __restrict__ bsum,
                          float* __restrict__ padd, unsigned int* __restrict__ pmax,
                          int* __restrict__ pcnt, int n) {
    __shared__ int s[256];
    int t = threadIdx.x;
    if (blockIdx.x < 48) {                 // fold: zero padd/pmax (12288 each) + pcnt
        int z = blockIdx.x * 256 + t;
        padd[z] = 0.f;
        pmax[z] = 0u;
        if (z < 64) pcnt[z] = 0;
    }
    int i = blockIdx.x * 256 + t;
    s[t] = (i < n) ? ideg[i] : 0;
    __syncthreads();
    for (int o = 128; o > 0; o >>= 1) {
        if (t < o) s[t] += s[t + o];
        __syncthreads();
    }
    if (t == 0) bsum[blockIdx.x] = s[0];
}

// ---------------- scan phase 2 (merged): every block redundantly scans bsum in LDS ----------
__global__ void scan_final(const int* __restrict__ ideg, const int* __restrict__ bsum,
                           int* __restrict__ offs, int* __restrict__ cur,
                           float* __restrict__ dinv, int n) {
    __shared__ int s[256];
    __shared__ int sb[256];
    int t = threadIdx.x;
    int i = blockIdx.x * 256 + t;
    int v = (i < n) ? ideg[i] : 0;
    s[t] = v;
    sb[t] = (t < SCAN_B) ? bsum[t] : 0;
    __syncthreads();
    for (int o = 1; o < 256; o <<= 1) {
        int u  = (t >= o) ? s[t - o] : 0;
        int ub = (t >= o) ? sb[t - o] : 0;
        __syncthreads();
        s[t] += u; sb[t] += ub;
        __syncthreads();
    }
    int base = (blockIdx.x == 0) ? 0 : sb[blockIdx.x - 1];   // exclusive block base
    int excl = base + s[t] - v;                              // exclusive prefix
    if (i < n) {
        offs[i] = excl; cur[i] = excl;
        dinv[i] = rsqrtf((float)v + 1.0f);
    }
    if (i == n - 1) offs[n] = excl + v;                      // total == E
}

// ---------------- FUSED: fill 256 edges + MFMA-matmul 16 nodes (PRE-SCALED P') ----------
// csr entry: u16 src only (2B — halves scatter write-back). The edge weight is folded
// into the stored rows: P'[s] = dinv[s] * (X@W1)[s], so agg needs no per-edge weight
// and fill needs NO random dinv[src] gather (was ~800K line-requests of TA service).
__global__ __launch_bounds__(256) void fused_fill_mm1(
        const int* __restrict__ ei, const float* __restrict__ dinv,
        int* __restrict__ cur, unsigned short* __restrict__ csr,
        const float* __restrict__ X, const __half* __restrict__ W1t,
        __half* __restrict__ Y16, int E) {
    constexpr int SX = 136;                // padded stride (halfs): b128 reads at conflict floor
    __shared__ __half sXh[16 * SX];
    int tid = threadIdx.x;

    // ---- phase 1: fill front-end (grid == E exactly; no guard, no dinv gather) ----
    int e = blockIdx.x * 256 + tid;
    unsigned short srcu = (unsigned short)(ei[e] & 0xFFFF);
    int d = ei[E + e];
    int pos = atomicAdd(&cur[d], 1);

    // ---- phase 2: B fragments global->reg (no LDS dependency) ----
    int lane = tid & 63;
    int r = lane & 15, h = lane >> 4;
    int w = tid >> 6;                      // ftile
    const half8* Brow = (const half8*)(W1t + (size_t)(w * 16 + r) * F_IN + h * 8);
    half8 b0 = Brow[0];
    half8 b1 = Brow[4];
    half8 b2 = Brow[8];
    half8 b3 = Brow[12];

    // ---- phase 3: stage X tile (fp32 -> fp16) ----
    int nodeBase = blockIdx.x * 16;        // 3125*16 == 50000 exactly
#pragma unroll
    for (int p = tid; p < 512; p += 256) { // 16 rows x 32 float4
        int row = p >> 5, c4 = p & 31;
        float4 v = *(const float4*)(X + (size_t)(nodeBase + row) * F_IN + c4 * 4);
        __half2 ab = __floats2half2_rn(v.x, v.y);
        __half2 cd = __floats2half2_rn(v.z, v.w);
        uint2 u; u.x = *(unsigned int*)&ab; u.y = *(unsigned int*)&cd;
        *(uint2*)&sXh[row * SX + c4 * 4] = u;
    }
    __syncthreads();

    // ---- phase 4: MFMA 16x64 = Xh[16x128] @ W1[128x64]; scale rows by dinv on store ----
    f32x4 acc = {0.f, 0.f, 0.f, 0.f};
    half8 a0 = *(const half8*)&sXh[r * SX +  0 + h * 8];
    half8 a1 = *(const half8*)&sXh[r * SX + 32 + h * 8];
    half8 a2 = *(const half8*)&sXh[r * SX + 64 + h * 8];
    half8 a3 = *(const half8*)&sXh[r * SX + 96 + h * 8];
    acc = __builtin_amdgcn_mfma_f32_16x16x32_f16(a0, b0, acc, 0, 0, 0);
    acc = __builtin_amdgcn_mfma_f32_16x16x32_f16(a1, b1, acc, 0, 0, 0);
    acc = __builtin_amdgcn_mfma_f32_16x16x32_f16(a2, b2, acc, 0, 0, 0);
    acc = __builtin_amdgcn_mfma_f32_16x16x32_f16(a3, b3, acc, 0, 0, 0);
    int nodeT = nodeBase + h * 4;
    float4 dv = *(const float4*)(dinv + nodeT);        // 16B-aligned (nodeT % 4 == 0)
    acc[0] *= dv.x; acc[1] *= dv.y; acc[2] *= dv.z; acc[3] *= dv.w;
#pragma unroll
    for (int reg = 0; reg < 4; ++reg)
        Y16[(size_t)(nodeT + reg) * 64 + w * 16 + r] = __float2half(acc[reg]);

    // ---- phase 5: deferred CSR store (2B scatter) ----
    csr[pos] = srcu;
}

// ---------------- dense matmul (layers 2,3) via MFMA: registers only, no LDS ----------------
// Output pre-scaled: P'[node] = dinv[node] * (h @ W).
__global__ __launch_bounds__(256) void matmul64_h(
        const __half* __restrict__ X, const __half* __restrict__ Wt,
        const float* __restrict__ dinv, __half* __restrict__ Y16, int n) {
    int tid = threadIdx.x;
    int nodeBase = blockIdx.x * 64;
    int lane = tid & 63;
    int r = lane & 15, h = lane >> 4;
    int w = tid >> 6;                      // node sub-tile (16 nodes)
    int rowA = nodeBase + w * 16 + r;      // tail over-read stays inside workspace; masked on store
    const half8* Arow = (const half8*)(X + (size_t)rowA * 64 + h * 8);
    half8 a0 = Arow[0];
    half8 a1 = Arow[4];
    int nodeT = nodeBase + w * 16 + h * 4;
    float4 dv = *(const float4*)(dinv + nodeT);        // tail reads stay inside workspace
#pragma unroll
    for (int ft = 0; ft < 4; ++ft) {
        const half8* Brow = (const half8*)(Wt + (size_t)(ft * 16 + r) * 64 + h * 8);
        half8 b0 = Brow[0];
        half8 b1 = Brow[4];
        f32x4 acc = {0.f, 0.f, 0.f, 0.f};
        acc = __builtin_amdgcn_mfma_f32_16x16x32_f16(a0, b0, acc, 0, 0, 0);
        acc = __builtin_amdgcn_mfma_f32_16x16x32_f16(a1, b1, acc, 0, 0, 0);
        acc[0] *= dv.x; acc[1] *= dv.y; acc[2] *= dv.z; acc[3] *= dv.w;
#pragma unroll
        for (int reg = 0; reg < 4; ++reg) {
            int node = nodeT + reg;
            if (node < n) Y16[(size_t)node * 64 + ft * 16 + r] = __float2half(acc[reg]);
        }
    }
}

// ---------------- agg v7: weight-free gather over pre-scaled P' ----------------
// One wave per node, LEAN. h = dinv[node]*(sum P'[src] + P'[self]) + b, relu.
// 8 groups x 4-edge chunks; partial group clamps to end-1 and masks (L1-hit, free).
__global__ void agg_kernel(const __half* __restrict__ hp16, const float* __restrict__ dinv,
                           const int* __restrict__ offs, const unsigned short* __restrict__ csr,
                           const float* __restrict__ b, __half* __restrict__ hout, int n) {
    int node = blockIdx.x * 4 + (threadIdx.x >> 6);
    if (node >= n) return;
    int lane = threadIdx.x & 63;
    int g = lane >> 3;                     // edge-group 0..7 (owns 4-edge chunk)
    int sub = lane & 7;                    // feature octet (feats 8*sub..8*sub+7)
    int beg = offs[node], end = offs[node + 1];

    // hoisted loads: overlap the gather loop
    float dn = dinv[node];
    uint4 sv = *(const uint4*)(hp16 + (size_t)node * 64 + sub * 8);
    float4 bA = *(const float4*)(b + sub * 8);
    float4 bB = *(const float4*)(b + sub * 8 + 4);

    float a0 = 0.f, a1 = 0.f, a2 = 0.f, a3 = 0.f;
    float a4 = 0.f, a5 = 0.f, a6 = 0.f, a7 = 0.f;
    int lim = end - 1;
#pragma unroll 1
    for (int base0 = beg; base0 < end; base0 += 32) {
        int base = base0 + g * 4;
        if (base < end) {                  // fully-invalid groups issue zero VMEM
            int i0 = base, i1 = min(base + 1, lim), i2 = min(base + 2, lim), i3 = min(base + 3, lim);
            unsigned short s0 = csr[i0], s1 = csr[i1], s2 = csr[i2], s3 = csr[i3];
            uint4 hv0 = *(const uint4*)(hp16 + (size_t)s0 * 64 + sub * 8);
            uint4 hv1 = *(const uint4*)(hp16 + (size_t)s1 * 64 + sub * 8);
            uint4 hv2 = *(const uint4*)(hp16 + (size_t)s2 * 64 + sub * 8);
            uint4 hv3 = *(const uint4*)(hp16 + (size_t)s3 * 64 + sub * 8);
#pragma unroll
            for (int j = 0; j < 4; ++j) {
                uint4 hvj = (j == 0) ? hv0 : (j == 1) ? hv1 : (j == 2) ? hv2 : hv3;
                float w = (base + j < end) ? 1.f : 0.f;     // mask partial group only
                float2 f01 = __half22float2(*(const __half2*)&hvj.x);
                float2 f23 = __half22float2(*(const __half2*)&hvj.y);
                float2 f45 = __half22float2(*(const __half2*)&hvj.z);
                float2 f67 = __half22float2(*(const __half2*)&hvj.w);
                a0 += f01.x * w; a1 += f01.y * w; a2 += f23.x * w; a3 += f23.y * w;
                a4 += f45.x * w; a5 += f45.y * w; a6 += f67.x * w; a7 += f67.y * w;
            }
        }
    }
#pragma unroll
    for (int m = 8; m <= 32; m <<= 1) {
        a0 += __shfl_xor(a0, m); a1 += __shfl_xor(a1, m);
        a2 += __shfl_xor(a2, m); a3 += __shfl_xor(a3, m);
        a4 += __shfl_xor(a4, m); a5 += __shfl_xor(a5, m);
        a6 += __shfl_xor(a6, m); a7 += __shfl_xor(a7, m);
    }

    float2 s01 = __half22float2(*(const __half2*)&sv.x);
    float2 s23 = __half22float2(*(const __half2*)&sv.y);
    float2 s45 = __half22float2(*(const __half2*)&sv.z);
    float2 s67 = __half22float2(*(const __half2*)&sv.w);
    float4 rA, rB;
    rA.x = dn * (a0 + s01.x) + bA.x;  rA.x = rA.x > 0.f ? rA.x : 0.f;
    rA.y = dn * (a1 + s01.y) + bA.y;  rA.y = rA.y > 0.f ? rA.y : 0.f;
    rA.z = dn * (a2 + s23.x) + bA.z;  rA.z = rA.z > 0.f ? rA.z : 0.f;
    rA.w = dn * (a3 + s23.y) + bA.w;  rA.w = rA.w > 0.f ? rA.w : 0.f;
    rB.x = dn * (a4 + s45.x) + bB.x;  rB.x = rB.x > 0.f ? rB.x : 0.f;
    rB.y = dn * (a5 + s45.y) + bB.y;  rB.y = rB.y > 0.f ? rB.y : 0.f;
    rB.z = dn * (a6 + s67.x) + bB.z;  rB.z = rB.z > 0.f ? rB.z : 0.f;
    rB.w = dn * (a7 + s67.y) + bB.w;  rB.w = rB.w > 0.f ? rB.w : 0.f;
    if (g == 0) {
        __half2 p0 = __floats2half2_rn(rA.x, rA.y);
        __half2 p1 = __floats2half2_rn(rA.z, rA.w);
        __half2 p2 = __floats2half2_rn(rB.x, rB.y);
        __half2 p3 = __floats2half2_rn(rB.z, rB.w);
        uint4 st;
        st.x = *(unsigned int*)&p0; st.y = *(unsigned int*)&p1;
        st.z = *(unsigned int*)&p2; st.w = *(unsigned int*)&p3;
        *(uint4*)(hout + (size_t)node * 64 + sub * 8) = st;
    }
}

// ---------------- pool v2: uint4-vectorized, 8 node-streams x 24 feature-octets ----------------
__global__ __launch_bounds__(192) void pool_kernel(
        const __half* __restrict__ h1, const __half* __restrict__ h2,
        const __half* __restrict__ h3, const int* __restrict__ batch,
        float* __restrict__ padd, unsigned int* __restrict__ pmax,
        int* __restrict__ pcnt, int n, int chunk) {
    __shared__ float lsum[8][192];
    __shared__ float lmax[8][192];
    int t = threadIdx.x;                   // 0..191
    int stream = t / 24;                   // 0..7
    int oct = t % 24;                      // 0..23
    int L = oct >> 3, sub = oct & 7;
    int f0 = L * 64 + sub * 8;
    const __half* src = (L == 0) ? h1 : (L == 1) ? h2 : h3;
    int start = blockIdx.x * chunk;
    int end = min(start + chunk, n);
    if (start >= end) return;
    int gtail = batch[end - 1];

    float s[8] = {0.f,0.f,0.f,0.f,0.f,0.f,0.f,0.f};
    float m[8] = {0.f,0.f,0.f,0.f,0.f,0.f,0.f,0.f};   // post-ReLU => 0 identity
    int cnt = 0;
    int node = start + stream;
    int gcur = (node < end) ? batch[node] : gtail;
    for (; node < end; node += 8) {
        int bg = batch[node];
        if (bg != gcur) {                  // graph boundary (rare): direct flush
#pragma unroll
            for (int j = 0; j < 8; ++j) {
                unsafeAtomicAdd(&padd[gcur * 192 + f0 + j], s[j]);
                atomicMax(&pmax[gcur * 192 + f0 + j], __float_as_uint(m[j]));
                s[j] = 0.f; m[j] = 0.f;
            }
            if (oct == 0) { atomicAdd(&pcnt[gcur], cnt); cnt = 0; }
            gcur = bg;
        }
        uint4 hv = *(const uint4*)(src + (size_t)node * 64 + sub * 8);
        const __half2* hp = (const __half2*)&hv;
#pragma unroll
        for (int q = 0; q < 4; ++q) {
            float2 f2 = __half22float2(hp[q]);
            s[2*q]   += f2.x;  m[2*q]   = fmaxf(m[2*q],   f2.x);
            s[2*q+1] += f2.y;  m[2*q+1] = fmaxf(m[2*q+1], f2.y);
        }
        if (oct == 0) ++cnt;
    }
    if (oct == 0 && cnt) atomicAdd(&pcnt[gcur], cnt);
    if (gcur != gtail) {                   // stream ended before last boundary (rare)
#pragma unroll
        for (int j = 0; j < 8; ++j) {
            unsafeAtomicAdd(&padd[gcur * 192 + f0 + j], s[j]);
            atomicMax(&pmax[gcur * 192 + f0 + j], __float_as_uint(m[j]));
            s[j] = 0.f; m[j] = 0.f;
        }
    }
#pragma unroll
    for (int j = 0; j < 8; ++j) {
        lsum[stream][f0 + j] = s[j];
        lmax[stream][f0 + j] = m[j];
    }
    __syncthreads();
    float ts = 0.f, tm = 0.f;
#pragma unroll
    for (int st = 0; st < 8; ++st) {
        ts += lsum[st][t];
        tm = fmaxf(tm, lmax[st][t]);
    }
    unsafeAtomicAdd(&padd[gtail * 192 + t], ts);
    atomicMax(&pmax[gtail * 192 + t], __float_as_uint(tm));
}

// ---------------- per-graph MLP + log_softmax ----------------
__global__ void mlp_kernel(const float* __restrict__ padd, const unsigned int* __restrict__ pmax,
                           const int* __restrict__ pcnt,
                           const float* __restrict__ lin1_W, const float* __restrict__ lin1_b,
                           const float* __restrict__ lin2_W, const float* __restrict__ lin2_b,
                           float* __restrict__ out) {
    int g = blockIdx.x;     // 64 blocks x 64 threads
    int t = threadIdx.x;
    __shared__ float gv[576];
    __shared__ float hid[64];
    float cnt = (float)pcnt[g];
    for (int i = t; i < 192; i += 64) {
        float a = padd[g * 192 + i];
        gv[i] = a;                                   // add
        gv[192 + i] = a / cnt;                       // mean
        gv[384 + i] = __uint_as_float(pmax[g * 192 + i]);  // max
    }
    __syncthreads();
    float acc = lin1_b[t];
#pragma unroll 8
    for (int k = 0; k < 576; ++k) acc += gv[k] * lin1_W[k * 64 + t];
    hid[t] = acc > 0.0f ? acc : 0.0f;
    __syncthreads();
    if (t == 0) {
        float l0 = lin2_b[0], l1 = lin2_b[1];
        for (int k = 0; k < 64; ++k) {
            l0 += hid[k] * lin2_W[k * 2 + 0];
            l1 += hid[k] * lin2_W[k * 2 + 1];
        }
        float m = fmaxf(l0, l1);
        float lse = m + logf(expf(l0 - m) + expf(l1 - m));
        out[g * 2 + 0] = l0 - lse;
        out[g * 2 + 1] = l1 - lse;
    }
}

extern "C" void kernel_launch(void* const* d_in, const int* in_sizes, int n_in,
                              void* d_out, int out_size, void* d_ws, size_t ws_size,
                              hipStream_t stream) {
    const float* x      = (const float*)d_in[0];
    const float* W1     = (const float*)d_in[1];
    const float* b1     = (const float*)d_in[2];
    const float* W2     = (const float*)d_in[3];
    const float* b2     = (const float*)d_in[4];
    const float* W3     = (const float*)d_in[5];
    const float* b3     = (const float*)d_in[6];
    const float* lin1_W = (const float*)d_in[7];
    const float* lin1_b = (const float*)d_in[8];
    const float* lin2_W = (const float*)d_in[9];
    const float* lin2_b = (const float*)d_in[10];
    const int*   ei     = (const int*)d_in[11];
    const int*   batch  = (const int*)d_in[12];
    float* out = (float*)d_out;

    // Workspace ~28 MB (R0 lesson: stay well under budget)
    char* ws = (char*)d_ws;
    size_t off = 0;
    auto alloc = [&](size_t bytes) {
        void* p = ws + off;
        off = (off + bytes + 255) & ~(size_t)255;
        return p;
    };
    int*   ideg    = (int*)  alloc(N_NODES * 4);
    float* dinv    = (float*)alloc(N_NODES * 4);
    int*   offs    = (int*)  alloc((N_NODES + 1) * 4);
    int*   cur     = (int*)  alloc(N_NODES * 4);
    int*   bsum    = (int*)  alloc(SCAN_B * 4);
    unsigned short* csr = (unsigned short*)alloc((size_t)N_EDGES * 2);   // u16 src only
    __half* P      = (__half*)alloc((size_t)N_NODES * 64 * 2);   // pre-scaled P', reused x3
    __half* h1     = (__half*)alloc((size_t)N_NODES * 64 * 2);
    __half* h2     = (__half*)alloc((size_t)N_NODES * 64 * 2);
    __half* h3     = (__half*)alloc((size_t)N_NODES * 64 * 2);
    __half* W1t    = (__half*)alloc(64 * 128 * 2);
    __half* W2t    = (__half*)alloc(64 * 64 * 2);
    __half* W3t    = (__half*)alloc(64 * 64 * 2);
    float* padd    = (float*)alloc(N_GRAPHS * 192 * 4);
    unsigned int* pmax = (unsigned int*)alloc(N_GRAPHS * 192 * 4);
    int*   pcnt    = (int*) alloc(N_GRAPHS * 4);

    // preamble: 3 kernels + 1 memset (pack/zeroing folded in)
    hipMemsetAsync(ideg, 0, N_NODES * 4, stream);
    deg_pack<<<(N_EDGES / 4 + 255) / 256, 256, 0, stream>>>(ei, ideg, N_EDGES,
                                                            W1, W2, W3, W1t, W2t, W3t);
    scan_part <<<SCAN_B, 256, 0, stream>>>(ideg, bsum, padd, pmax, pcnt, N_NODES);
    scan_final<<<SCAN_B, 256, 0, stream>>>(ideg, bsum, offs, cur, dinv, N_NODES);

    const int mmGrid  = (N_NODES + 63) / 64;     // 782 (64-node MFMA tiles)
    const int aggGrid = (N_NODES + 3) / 4;       // 12500 (one wave per node)

    // layer 1: fill + dinv*(X@W1) -> P'
    fused_fill_mm1<<<FUSE_B, 256, 0, stream>>>(ei, dinv, cur, csr, x, W1t, P, N_EDGES);
    agg_kernel<<<aggGrid, 256, 0, stream>>>(P, dinv, offs, csr, b1, h1, N_NODES);
    // layer 2
    matmul64_h<<<mmGrid, 256, 0, stream>>>(h1, W2t, dinv, P, N_NODES);
    agg_kernel<<<aggGrid, 256, 0, stream>>>(P, dinv, offs, csr, b2, h2, N_NODES);
    // layer 3
    matmul64_h<<<mmGrid, 256, 0, stream>>>(h2, W3t, dinv, P, N_NODES);
    agg_kernel<<<aggGrid, 256, 0, stream>>>(P, dinv, offs, csr, b3, h3, N_NODES);

    // pooling (vectorized) + head
    const int chunk = (N_NODES + 511) / 512;           // 98 nodes/block
    pool_kernel<<<512, 192, 0, stream>>>(h1, h2, h3, batch, padd, pmax, pcnt, N_NODES, chunk);
    mlp_kernel<<<N_GRAPHS, 64, 0, stream>>>(padd, pmax, pcnt, lin1_W, lin1_b, lin2_W, lin2_b, out);
}

// Round 8
// 281.018 us; speedup vs baseline: 1.1384x; 1.1384x over previous
//
#include <hip/hip_runtime.h>
#include <hip/hip_fp16.h>

#define N_NODES 50000
#define N_EDGES 800000
#define F_IN 128
#define HID 64
#define N_GRAPHS 64

#define SCAN_B ((N_NODES + 255) / 256)     // 196 blocks
#define FUSE_B ((N_EDGES + 255) / 256)     // 3125 blocks; == N_NODES/16 exactly

typedef _Float16 half8 __attribute__((ext_vector_type(8)));
typedef float f32x4 __attribute__((ext_vector_type(4)));

// ---------------- degree + per-edge rank (counting-sort front half) + weight pack ----------
// rank[e] = this edge's slot index within its dst segment (atomicAdd return value).
// Removes the 800K device-scope atomics from the hot fill kernel entirely.
__global__ void deg_pack(const int* __restrict__ ei, int* __restrict__ ideg,
                         unsigned short* __restrict__ rank, int* __restrict__ pcnt, int E,
                         const float* __restrict__ W1, const float* __restrict__ W2,
                         const float* __restrict__ W3,
                         __half* __restrict__ W1t, __half* __restrict__ W2t,
                         __half* __restrict__ W3t) {
    int i = blockIdx.x * blockDim.x + threadIdx.x;
    if (i * 4 < E) {
        int4 d = ((const int4*)(ei + E))[i];   // dst row contiguous
        unsigned short r0 = (unsigned short)atomicAdd(&ideg[d.x], 1);
        unsigned short r1 = (unsigned short)atomicAdd(&ideg[d.y], 1);
        unsigned short r2 = (unsigned short)atomicAdd(&ideg[d.z], 1);
        unsigned short r3 = (unsigned short)atomicAdd(&ideg[d.w], 1);
        ushort4 rr; rr.x = r0; rr.y = r1; rr.z = r2; rr.w = r3;
        *(ushort4*)(rank + i * 4) = rr;        // coalesced 8B store
    }
    if (i < 64) pcnt[i] = 0;                   // zero before scan_part's histogram atomics
    // fold: transpose+cast weights (16384 lanes; first 64 blocks)
    if (i < 8192) {                                   // W1t: [64 f][128 k]
        int f = i >> 7, k = i & 127;
        W1t[i] = __float2half(W1[k * 64 + f]);
    } else if (i < 12288) {                           // W2t: [64 f][64 k]
        int j = i - 8192;
        int f = j >> 6, k = j & 63;
        W2t[j] = __float2half(W2[k * 64 + f]);
    } else if (i < 16384) {                           // W3t: [64 f][64 k]
        int l = i - 12288;
        int f = l >> 6, k = l & 63;
        W3t[l] = __float2half(W3[k * 64 + f]);
    }
}

// ---------------- scan phase 1: per-block sums (+ fold: zero pool bufs, pcnt histogram) ----
__global__ void scan_part(const int* __restrict__ ideg, int* __restrict__ bsum,
                          const int* __restrict__ batch,
                          float* __restrict__ padd, unsigned int* __restrict__ pmax,
                          int* __restrict__ pcnt, int n) {
    __shared__ int s[256];
    __shared__ int hcnt[N_GRAPHS];
    int t = threadIdx.x;
    if (blockIdx.x < 48) {                 // fold: zero padd/pmax (12288 each)
        int z = blockIdx.x * 256 + t;
        padd[z] = 0.f;
        pmax[z] = 0u;
    }
    if (t < N_GRAPHS) hcnt[t] = 0;
    int i = blockIdx.x * 256 + t;
    s[t] = (i < n) ? ideg[i] : 0;
    __syncthreads();
    if (i < n) atomicAdd(&hcnt[batch[i]], 1);    // fold: per-graph node counts
    for (int o = 128; o > 0; o >>= 1) {
        if (t < o) s[t] += s[t + o];
        __syncthreads();
    }
    if (t == 0) bsum[blockIdx.x] = s[0];
    if (t < N_GRAPHS && hcnt[t]) atomicAdd(&pcnt[t], hcnt[t]);
}

// ---------------- scan phase 2 (merged): every block redundantly scans bsum in LDS ----------
__global__ void scan_final(const int* __restrict__ ideg, const int* __restrict__ bsum,
                           int* __restrict__ offs, float* __restrict__ dinv, int n) {
    __shared__ int s[256];
    __shared__ int sb[256];
    int t = threadIdx.x;
    int i = blockIdx.x * 256 + t;
    int v = (i < n) ? ideg[i] : 0;
    s[t] = v;
    sb[t] = (t < SCAN_B) ? bsum[t] : 0;
    __syncthreads();
    for (int o = 1; o < 256; o <<= 1) {
        int u  = (t >= o) ? s[t - o] : 0;
        int ub = (t >= o) ? sb[t - o] : 0;
        __syncthreads();
        s[t] += u; sb[t] += ub;
        __syncthreads();
    }
    int base = (blockIdx.x == 0) ? 0 : sb[blockIdx.x - 1];   // exclusive block base
    int excl = base + s[t] - v;                              // exclusive prefix
    if (i < n) {
        offs[i] = excl;
        dinv[i] = rsqrtf((float)v + 1.0f);
    }
    if (i == n - 1) offs[n] = excl + v;                      // total == E
}

// ---------------- FUSED: fill 256 edges + MFMA-matmul 16 nodes (PRE-SCALED P') ----------
// csr entry: u16 src. pos = offs[d] + rank[e] — NO atomic in this kernel; offs is
// read-only (XCD-local L2 replication, no coherence RMW). P'[s] = dinv[s]*(X@W1)[s].
__global__ __launch_bounds__(256) void fused_fill_mm1(
        const int* __restrict__ ei, const float* __restrict__ dinv,
        const int* __restrict__ offs, const unsigned short* __restrict__ rank,
        unsigned short* __restrict__ csr,
        const float* __restrict__ X, const __half* __restrict__ W1t,
        __half* __restrict__ Y16, int E) {
    constexpr int SX = 136;                // padded stride (halfs): b128 reads at conflict floor
    __shared__ __half sXh[16 * SX];
    int tid = threadIdx.x;

    // ---- phase 1: fill front-end (no guard, no atomic) ----
    int e = blockIdx.x * 256 + tid;
    unsigned short srcu = (unsigned short)(ei[e] & 0xFFFF);
    int d = ei[E + e];
    int pos = offs[d] + (int)rank[e];      // random 4B gather + contiguous 2B load

    // ---- phase 2: B fragments global->reg (no LDS dependency) ----
    int lane = tid & 63;
    int r = lane & 15, h = lane >> 4;
    int w = tid >> 6;                      // ftile
    const half8* Brow = (const half8*)(W1t + (size_t)(w * 16 + r) * F_IN + h * 8);
    half8 b0 = Brow[0];
    half8 b1 = Brow[4];
    half8 b2 = Brow[8];
    half8 b3 = Brow[12];

    // ---- phase 3: stage X tile (fp32 -> fp16) ----
    int nodeBase = blockIdx.x * 16;        // 3125*16 == 50000 exactly
#pragma unroll
    for (int p = tid; p < 512; p += 256) { // 16 rows x 32 float4
        int row = p >> 5, c4 = p & 31;
        float4 v = *(const float4*)(X + (size_t)(nodeBase + row) * F_IN + c4 * 4);
        __half2 ab = __floats2half2_rn(v.x, v.y);
        __half2 cd = __floats2half2_rn(v.z, v.w);
        uint2 u; u.x = *(unsigned int*)&ab; u.y = *(unsigned int*)&cd;
        *(uint2*)&sXh[row * SX + c4 * 4] = u;
    }
    __syncthreads();

    // ---- phase 4: MFMA 16x64 = Xh[16x128] @ W1[128x64]; scale rows by dinv on store ----
    f32x4 acc = {0.f, 0.f, 0.f, 0.f};
    half8 a0 = *(const half8*)&sXh[r * SX +  0 + h * 8];
    half8 a1 = *(const half8*)&sXh[r * SX + 32 + h * 8];
    half8 a2 = *(const half8*)&sXh[r * SX + 64 + h * 8];
    half8 a3 = *(const half8*)&sXh[r * SX + 96 + h * 8];
    acc = __builtin_amdgcn_mfma_f32_16x16x32_f16(a0, b0, acc, 0, 0, 0);
    acc = __builtin_amdgcn_mfma_f32_16x16x32_f16(a1, b1, acc, 0, 0, 0);
    acc = __builtin_amdgcn_mfma_f32_16x16x32_f16(a2, b2, acc, 0, 0, 0);
    acc = __builtin_amdgcn_mfma_f32_16x16x32_f16(a3, b3, acc, 0, 0, 0);
    int nodeT = nodeBase + h * 4;
    float4 dv = *(const float4*)(dinv + nodeT);        // 16B-aligned (nodeT % 4 == 0)
    acc[0] *= dv.x; acc[1] *= dv.y; acc[2] *= dv.z; acc[3] *= dv.w;
#pragma unroll
    for (int reg = 0; reg < 4; ++reg)
        Y16[(size_t)(nodeT + reg) * 64 + w * 16 + r] = __float2half(acc[reg]);

    // ---- phase 5: deferred CSR store (2B scatter) ----
    csr[pos] = srcu;
}

// ---------------- dense matmul (layers 2,3) via MFMA: registers only, no LDS ----------------
// Output pre-scaled: P'[node] = dinv[node] * (h @ W).
__global__ __launch_bounds__(256) void matmul64_h(
        const __half* __restrict__ X, const __half* __restrict__ Wt,
        const float* __restrict__ dinv, __half* __restrict__ Y16, int n) {
    int tid = threadIdx.x;
    int nodeBase = blockIdx.x * 64;
    int lane = tid & 63;
    int r = lane & 15, h = lane >> 4;
    int w = tid >> 6;                      // node sub-tile (16 nodes)
    int rowA = nodeBase + w * 16 + r;      // tail over-read stays inside workspace; masked on store
    const half8* Arow = (const half8*)(X + (size_t)rowA * 64 + h * 8);
    half8 a0 = Arow[0];
    half8 a1 = Arow[4];
    int nodeT = nodeBase + w * 16 + h * 4;
    float4 dv = *(const float4*)(dinv + nodeT);        // tail reads stay inside workspace
#pragma unroll
    for (int ft = 0; ft < 4; ++ft) {
        const half8* Brow = (const half8*)(Wt + (size_t)(ft * 16 + r) * 64 + h * 8);
        half8 b0 = Brow[0];
        half8 b1 = Brow[4];
        f32x4 acc = {0.f, 0.f, 0.f, 0.f};
        acc = __builtin_amdgcn_mfma_f32_16x16x32_f16(a0, b0, acc, 0, 0, 0);
        acc = __builtin_amdgcn_mfma_f32_16x16x32_f16(a1, b1, acc, 0, 0, 0);
        acc[0] *= dv.x; acc[1] *= dv.y; acc[2] *= dv.z; acc[3] *= dv.w;
#pragma unroll
        for (int reg = 0; reg < 4; ++reg) {
            int node = nodeT + reg;
            if (node < n) Y16[(size_t)node * 64 + ft * 16 + r] = __float2half(acc[reg]);
        }
    }
}

// ---------------- agg v7: weight-free gather over pre-scaled P' ----------------
// One wave per node, LEAN. h = dinv[node]*(sum P'[src] + P'[self]) + b, relu.
__global__ void agg_kernel(const __half* __restrict__ hp16, const float* __restrict__ dinv,
                           const int* __restrict__ offs, const unsigned short* __restrict__ csr,
                           const float* __restrict__ b, __half* __restrict__ hout, int n) {
    int node = blockIdx.x * 4 + (threadIdx.x >> 6);
    if (node >= n) return;
    int lane = threadIdx.x & 63;
    int g = lane >> 3;                     // edge-group 0..7 (owns 4-edge chunk)
    int sub = lane & 7;                    // feature octet (feats 8*sub..8*sub+7)
    int beg = offs[node], end = offs[node + 1];

    // hoisted loads: overlap the gather loop
    float dn = dinv[node];
    uint4 sv = *(const uint4*)(hp16 + (size_t)node * 64 + sub * 8);
    float4 bA = *(const float4*)(b + sub * 8);
    float4 bB = *(const float4*)(b + sub * 8 + 4);

    float a0 = 0.f, a1 = 0.f, a2 = 0.f, a3 = 0.f;
    float a4 = 0.f, a5 = 0.f, a6 = 0.f, a7 = 0.f;
    int lim = end - 1;
#pragma unroll 1
    for (int base0 = beg; base0 < end; base0 += 32) {
        int base = base0 + g * 4;
        if (base < end) {                  // fully-invalid groups issue zero VMEM
            int i0 = base, i1 = min(base + 1, lim), i2 = min(base + 2, lim), i3 = min(base + 3, lim);
            unsigned short s0 = csr[i0], s1 = csr[i1], s2 = csr[i2], s3 = csr[i3];
            uint4 hv0 = *(const uint4*)(hp16 + (size_t)s0 * 64 + sub * 8);
            uint4 hv1 = *(const uint4*)(hp16 + (size_t)s1 * 64 + sub * 8);
            uint4 hv2 = *(const uint4*)(hp16 + (size_t)s2 * 64 + sub * 8);
            uint4 hv3 = *(const uint4*)(hp16 + (size_t)s3 * 64 + sub * 8);
#pragma unroll
            for (int j = 0; j < 4; ++j) {
                uint4 hvj = (j == 0) ? hv0 : (j == 1) ? hv1 : (j == 2) ? hv2 : hv3;
                float w = (base + j < end) ? 1.f : 0.f;     // mask partial group only
                float2 f01 = __half22float2(*(const __half2*)&hvj.x);
                float2 f23 = __half22float2(*(const __half2*)&hvj.y);
                float2 f45 = __half22float2(*(const __half2*)&hvj.z);
                float2 f67 = __half22float2(*(const __half2*)&hvj.w);
                a0 += f01.x * w; a1 += f01.y * w; a2 += f23.x * w; a3 += f23.y * w;
                a4 += f45.x * w; a5 += f45.y * w; a6 += f67.x * w; a7 += f67.y * w;
            }
        }
    }
#pragma unroll
    for (int m = 8; m <= 32; m <<= 1) {
        a0 += __shfl_xor(a0, m); a1 += __shfl_xor(a1, m);
        a2 += __shfl_xor(a2, m); a3 += __shfl_xor(a3, m);
        a4 += __shfl_xor(a4, m); a5 += __shfl_xor(a5, m);
        a6 += __shfl_xor(a6, m); a7 += __shfl_xor(a7, m);
    }

    float2 s01 = __half22float2(*(const __half2*)&sv.x);
    float2 s23 = __half22float2(*(const __half2*)&sv.y);
    float2 s45 = __half22float2(*(const __half2*)&sv.z);
    float2 s67 = __half22float2(*(const __half2*)&sv.w);
    float4 rA, rB;
    rA.x = dn * (a0 + s01.x) + bA.x;  rA.x = rA.x > 0.f ? rA.x : 0.f;
    rA.y = dn * (a1 + s01.y) + bA.y;  rA.y = rA.y > 0.f ? rA.y : 0.f;
    rA.z = dn * (a2 + s23.x) + bA.z;  rA.z = rA.z > 0.f ? rA.z : 0.f;
    rA.w = dn * (a3 + s23.y) + bA.w;  rA.w = rA.w > 0.f ? rA.w : 0.f;
    rB.x = dn * (a4 + s45.x) + bB.x;  rB.x = rB.x > 0.f ? rB.x : 0.f;
    rB.y = dn * (a5 + s45.y) + bB.y;  rB.y = rB.y > 0.f ? rB.y : 0.f;
    rB.z = dn * (a6 + s67.x) + bB.z;  rB.z = rB.z > 0.f ? rB.z : 0.f;
    rB.w = dn * (a7 + s67.y) + bB.w;  rB.w = rB.w > 0.f ? rB.w : 0.f;
    if (g == 0) {
        __half2 p0 = __floats2half2_rn(rA.x, rA.y);
        __half2 p1 = __floats2half2_rn(rA.z, rA.w);
        __half2 p2 = __floats2half2_rn(rB.x, rB.y);
        __half2 p3 = __floats2half2_rn(rB.z, rB.w);
        uint4 st;
        st.x = *(unsigned int*)&p0; st.y = *(unsigned int*)&p1;
        st.z = *(unsigned int*)&p2; st.w = *(unsigned int*)&p3;
        *(uint4*)(hout + (size_t)node * 64 + sub * 8) = st;
    }
}

// ---------------- pool v3: uint4-vectorized, 8 node-streams x 24 feature-octets ----------------
// (pcnt now computed in scan_part)
__global__ __launch_bounds__(192) void pool_kernel(
        const __half* __restrict__ h1, const __half* __restrict__ h2,
        const __half* __restrict__ h3, const int* __restrict__ batch,
        float* __restrict__ padd, unsigned int* __restrict__ pmax, int n, int chunk) {
    __shared__ float lsum[8][192];
    __shared__ float lmax[8][192];
    int t = threadIdx.x;                   // 0..191
    int stream = t / 24;                   // 0..7
    int oct = t % 24;                      // 0..23
    int L = oct >> 3, sub = oct & 7;
    int f0 = L * 64 + sub * 8;
    const __half* src = (L == 0) ? h1 : (L == 1) ? h2 : h3;
    int start = blockIdx.x * chunk;
    int end = min(start + chunk, n);
    if (start >= end) return;
    int gtail = batch[end - 1];

    float s[8] = {0.f,0.f,0.f,0.f,0.f,0.f,0.f,0.f};
    float m[8] = {0.f,0.f,0.f,0.f,0.f,0.f,0.f,0.f};   // post-ReLU => 0 identity
    int node = start + stream;
    int gcur = (node < end) ? batch[node] : gtail;
    for (; node < end; node += 8) {
        int bg = batch[node];
        if (bg != gcur) {                  // graph boundary (rare): direct flush
#pragma unroll
            for (int j = 0; j < 8; ++j) {
                unsafeAtomicAdd(&padd[gcur * 192 + f0 + j], s[j]);
                atomicMax(&pmax[gcur * 192 + f0 + j], __float_as_uint(m[j]));
                s[j] = 0.f; m[j] = 0.f;
            }
            gcur = bg;
        }
        uint4 hv = *(const uint4*)(src + (size_t)node * 64 + sub * 8);
        const __half2* hp = (const __half2*)&hv;
#pragma unroll
        for (int q = 0; q < 4; ++q) {
            float2 f2 = __half22float2(hp[q]);
            s[2*q]   += f2.x;  m[2*q]   = fmaxf(m[2*q],   f2.x);
            s[2*q+1] += f2.y;  m[2*q+1] = fmaxf(m[2*q+1], f2.y);
        }
    }
    if (gcur != gtail) {                   // stream ended before last boundary (rare)
#pragma unroll
        for (int j = 0; j < 8; ++j) {
            unsafeAtomicAdd(&padd[gcur * 192 + f0 + j], s[j]);
            atomicMax(&pmax[gcur * 192 + f0 + j], __float_as_uint(m[j]));
            s[j] = 0.f; m[j] = 0.f;
        }
    }
#pragma unroll
    for (int j = 0; j < 8; ++j) {
        lsum[stream][f0 + j] = s[j];
        lmax[stream][f0 + j] = m[j];
    }
    __syncthreads();
    float ts = 0.f, tm = 0.f;
#pragma unroll
    for (int st = 0; st < 8; ++st) {
        ts += lsum[st][t];
        tm = fmaxf(tm, lmax[st][t]);
    }
    unsafeAtomicAdd(&padd[gtail * 192 + t], ts);
    atomicMax(&pmax[gtail * 192 + t], __float_as_uint(tm));
}

// ---------------- per-graph MLP + log_softmax ----------------
__global__ void mlp_kernel(const float* __restrict__ padd, const unsigned int* __restrict__ pmax,
                           const int* __restrict__ pcnt,
                           const float* __restrict__ lin1_W, const float* __restrict__ lin1_b,
                           const float* __restrict__ lin2_W, const float* __restrict__ lin2_b,
                           float* __restrict__ out) {
    int g = blockIdx.x;     // 64 blocks x 64 threads
    int t = threadIdx.x;
    __shared__ float gv[576];
    __shared__ float hid[64];
    float cnt = (float)pcnt[g];
    for (int i = t; i < 192; i += 64) {
        float a = padd[g * 192 + i];
        gv[i] = a;                                   // add
        gv[192 + i] = a / cnt;                       // mean
        gv[384 + i] = __uint_as_float(pmax[g * 192 + i]);  // max
    }
    __syncthreads();
    float acc = lin1_b[t];
#pragma unroll 8
    for (int k = 0; k < 576; ++k) acc += gv[k] * lin1_W[k * 64 + t];
    hid[t] = acc > 0.0f ? acc : 0.0f;
    __syncthreads();
    if (t == 0) {
        float l0 = lin2_b[0], l1 = lin2_b[1];
        for (int k = 0; k < 64; ++k) {
            l0 += hid[k] * lin2_W[k * 2 + 0];
            l1 += hid[k] * lin2_W[k * 2 + 1];
        }
        float m = fmaxf(l0, l1);
        float lse = m + logf(expf(l0 - m) + expf(l1 - m));
        out[g * 2 + 0] = l0 - lse;
        out[g * 2 + 1] = l1 - lse;
    }
}

extern "C" void kernel_launch(void* const* d_in, const int* in_sizes, int n_in,
                              void* d_out, int out_size, void* d_ws, size_t ws_size,
                              hipStream_t stream) {
    const float* x      = (const float*)d_in[0];
    const float* W1     = (const float*)d_in[1];
    const float* b1     = (const float*)d_in[2];
    const float* W2     = (const float*)d_in[3];
    const float* b2     = (const float*)d_in[4];
    const float* W3     = (const float*)d_in[5];
    const float* b3     = (const float*)d_in[6];
    const float* lin1_W = (const float*)d_in[7];
    const float* lin1_b = (const float*)d_in[8];
    const float* lin2_W = (const float*)d_in[9];
    const float* lin2_b = (const float*)d_in[10];
    const int*   ei     = (const int*)d_in[11];
    const int*   batch  = (const int*)d_in[12];
    float* out = (float*)d_out;

    // Workspace ~29 MB (R0 lesson: stay well under budget)
    char* ws = (char*)d_ws;
    size_t off = 0;
    auto alloc = [&](size_t bytes) {
        void* p = ws + off;
        off = (off + bytes + 255) & ~(size_t)255;
        return p;
    };
    int*   ideg    = (int*)  alloc(N_NODES * 4);
    float* dinv    = (float*)alloc(N_NODES * 4);
    int*   offs    = (int*)  alloc((N_NODES + 1) * 4);
    int*   bsum    = (int*)  alloc(SCAN_B * 4);
    unsigned short* rank = (unsigned short*)alloc((size_t)N_EDGES * 2);
    unsigned short* csr  = (unsigned short*)alloc((size_t)N_EDGES * 2);   // u16 src only
    __half* P      = (__half*)alloc((size_t)N_NODES * 64 * 2);   // pre-scaled P', reused x3
    __half* h1     = (__half*)alloc((size_t)N_NODES * 64 * 2);
    __half* h2     = (__half*)alloc((size_t)N_NODES * 64 * 2);
    __half* h3     = (__half*)alloc((size_t)N_NODES * 64 * 2);
    __half* W1t    = (__half*)alloc(64 * 128 * 2);
    __half* W2t    = (__half*)alloc(64 * 64 * 2);
    __half* W3t    = (__half*)alloc(64 * 64 * 2);
    float* padd    = (float*)alloc(N_GRAPHS * 192 * 4);
    unsigned int* pmax = (unsigned int*)alloc(N_GRAPHS * 192 * 4);
    int*   pcnt    = (int*) alloc(N_GRAPHS * 4);

    // preamble: 3 kernels + 1 memset (pack/zeroing/pcnt folded in)
    hipMemsetAsync(ideg, 0, N_NODES * 4, stream);
    deg_pack<<<(N_EDGES / 4 + 255) / 256, 256, 0, stream>>>(ei, ideg, rank, pcnt, N_EDGES,
                                                            W1, W2, W3, W1t, W2t, W3t);
    scan_part <<<SCAN_B, 256, 0, stream>>>(ideg, bsum, batch, padd, pmax, pcnt, N_NODES);
    scan_final<<<SCAN_B, 256, 0, stream>>>(ideg, bsum, offs, dinv, N_NODES);

    const int mmGrid  = (N_NODES + 63) / 64;     // 782 (64-node MFMA tiles)
    const int aggGrid = (N_NODES + 3) / 4;       // 12500 (one wave per node)

    // layer 1: fill + dinv*(X@W1) -> P'
    fused_fill_mm1<<<FUSE_B, 256, 0, stream>>>(ei, dinv, offs, rank, csr, x, W1t, P, N_EDGES);
    agg_kernel<<<aggGrid, 256, 0, stream>>>(P, dinv, offs, csr, b1, h1, N_NODES);
    // layer 2
    matmul64_h<<<mmGrid, 256, 0, stream>>>(h1, W2t, dinv, P, N_NODES);
    agg_kernel<<<aggGrid, 256, 0, stream>>>(P, dinv, offs, csr, b2, h2, N_NODES);
    // layer 3
    matmul64_h<<<mmGrid, 256, 0, stream>>>(h2, W3t, dinv, P, N_NODES);
    agg_kernel<<<aggGrid, 256, 0, stream>>>(P, dinv, offs, csr, b3, h3, N_NODES);

    // pooling (vectorized) + head
    const int chunk = (N_NODES + 511) / 512;           // 98 nodes/block
    pool_kernel<<<512, 192, 0, stream>>>(h1, h2, h3, batch, padd, pmax, N_NODES, chunk);
    mlp_kernel<<<N_GRAPHS, 64, 0, stream>>>(padd, pmax, pcnt, lin1_W, lin1_b, lin2_W, lin2_b, out);
}